// Round 15
// baseline (463.941 us; speedup 1.0000x reference)
//
#include <hip/hip_runtime.h>
#include <hip/hip_bf16.h>

#define NN 20000
#define NE 160000
#define EF (NE + NN)          // edges + self loops
#define DD 128
#define HH 4
#define NPA (NN * DD)                       // pack_a elements
#define NPW (1024 * 128 + 128 * 128 + 1024) // pack_w elements
#define DEGB ((NE + 255) / 256)             // deg blocks in fused deg+pack

typedef unsigned short u16;
typedef unsigned int u32;

using short8  = __attribute__((ext_vector_type(8))) short;
using ushort8 = __attribute__((ext_vector_type(8))) unsigned short;
using float4v = __attribute__((ext_vector_type(4))) float;

__device__ __forceinline__ float bf2f(u16 u) {
    union { u32 i; float f; } c;
    c.i = ((u32)u) << 16;
    return c.f;
}
// round-to-nearest-even fp32 -> bf16 bits (finite inputs)
__device__ __forceinline__ u16 f2bf(float f) {
    union { float f; u32 u; } c;
    c.f = f;
    u32 u = c.u;
    u32 r = (u + 0x7fffu + ((u >> 16) & 1u)) >> 16;
    return (u16)r;
}

// ---------- utility ----------

__global__ void k_zero_i(int* __restrict__ p, int n) {
    int i = blockIdx.x * blockDim.x + threadIdx.x;
    if (i < n) p[i] = 0;
}

__global__ void k_zero_f(float* __restrict__ p, int n) {
    int i = blockIdx.x * blockDim.x + threadIdx.x;
    if (i < n) p[i] = 0.f;
}

// ---------- fused deg + pack (independent block ranges) ----------

__global__ void k_degpack(const int* __restrict__ ei, const float* __restrict__ ea,
                          const float* __restrict__ x,
                          const float* __restrict__ Wl, const float* __restrict__ Wr,
                          const float* __restrict__ bl, const float* __restrict__ br,
                          const float* __restrict__ Wf,
                          int* __restrict__ cnt, float* __restrict__ ea_sum,
                          u16* __restrict__ Axh, u16* __restrict__ Axl,
                          u16* __restrict__ W2Th, u16* __restrict__ W2Tl,
                          u16* __restrict__ WfTh, u16* __restrict__ WfTl,
                          float* __restrict__ bias2) {
    int gb = blockIdx.x;
    if (gb < DEGB) {
        int e = gb * 256 + threadIdx.x;
        if (e >= NE) return;
        int t = ei[NE + e];
        atomicAdd(&cnt[t], 1);
        atomicAdd(&ea_sum[t * 2 + 0], ea[e * 2 + 0]);
        atomicAdd(&ea_sum[t * 2 + 1], ea[e * 2 + 1]);
        return;
    }
    int i = (gb - DEGB) * 256 + threadIdx.x;
    if (i < NPA) {
        float a = x[i];
        u16 h = f2bf(a);
        Axh[i] = h;
        Axl[i] = f2bf(a - bf2f(h));
        return;
    }
    i -= NPA;
    if (i < 1024 * 128) {
        int n = i >> 7, k = i & 127;
        float w = (n < 512) ? Wl[k * 512 + n] : Wr[k * 512 + (n - 512)];
        u16 h = f2bf(w);
        W2Th[n * 128 + k] = h;
        W2Tl[n * 128 + k] = f2bf(w - bf2f(h));
    } else if (i < 1024 * 128 + 128 * 128) {
        int u = i - 1024 * 128;
        int n = u >> 7, k = u & 127;
        float w = Wf[k * 128 + n];
        u16 h = f2bf(w);
        WfTh[n * 128 + k] = h;
        WfTl[n * 128 + k] = f2bf(w - bf2f(h));
    } else if (i < NPW) {
        int n = i - (1024 * 128 + 128 * 128);
        bias2[n] = (n < 512) ? bl[n] : br[n - 512];
    }
}

// ---------- single-block shfl scan: rowptr = excl prefix of cnt+1 ----------

__global__ void k_scan(const int* __restrict__ cnt, int* __restrict__ rowptr) {
    __shared__ int wsum[16];
    __shared__ int s_base;
    int tid = threadIdx.x;           // 1024 threads = 16 waves
    int w = tid >> 6, l = tid & 63;
    if (tid == 0) { s_base = 0; rowptr[0] = 0; }
    __syncthreads();
    const int chunks = (NN + 1023) / 1024;
    for (int c = 0; c < chunks; ++c) {
        int i = c * 1024 + tid;
        int v = (i < NN) ? (cnt[i] + 1) : 0;
        #pragma unroll
        for (int off = 1; off < 64; off <<= 1) {
            int u = __shfl_up(v, off, 64);
            if (l >= off) v += u;
        }
        if (l == 63) wsum[w] = v;
        __syncthreads();
        if (w == 0) {
            int s = (l < 16) ? wsum[l] : 0;
            #pragma unroll
            for (int off = 1; off < 16; off <<= 1) {
                int u = __shfl_up(s, off, 64);
                if (l >= off) s += u;
            }
            if (l < 16) wsum[l] = s;   // inclusive wave sums
        }
        __syncthreads();
        int waveoff = (w > 0) ? wsum[w - 1] : 0;
        int incl = s_base + waveoff + v;
        if (i < NN) rowptr[i + 1] = incl;
        __syncthreads();
        if (tid == 1023) s_base = incl;
        __syncthreads();
    }
}

// ---------- fused fill + self-loop ----------

__global__ void k_fill(const int* __restrict__ ei, const float* __restrict__ ea,
                       const int* __restrict__ rowptr, int* __restrict__ fillc,
                       const int* __restrict__ cnt, const float* __restrict__ ea_sum,
                       int* __restrict__ srcs,
                       float* __restrict__ fa0, float* __restrict__ fa1) {
    int e = blockIdx.x * blockDim.x + threadIdx.x;
    if (e < NE) {
        int s = ei[e], t = ei[NE + e];
        int pos = atomicAdd(&fillc[t], 1);
        int slot = rowptr[t] + pos;
        srcs[slot] = s;
        fa0[slot] = ea[e * 2];
        fa1[slot] = ea[e * 2 + 1];
    } else if (e < NE + NN) {
        int n = e - NE;
        int slot = rowptr[n + 1] - 1;   // self-loop is last slot
        srcs[slot] = n;
        float c = fmaxf((float)cnt[n], 1.f);
        fa0[slot] = ea_sum[n * 2 + 0] / c;
        fa1[slot] = ea_sum[n * 2 + 1] / c;
    }
}

// ---------- split-bf16 MFMA GEMM ----------
// XOR-swizzled LDS (KS=128, chunk c of row r stored at c^(r&15)) -> 0 bank
// conflicts (R14 measured 1.9M with +8 padding), 48 KB -> 3 blocks/CU.
// 3-term split: ah*bh + ah*bl + al*bh; A-lo in registers; 2 bands per block.
// xr output (bands n0>=512) written as bf16 (error budget analysis: ~1e-4
// output absmax contribution vs 4.5e-4 threshold).

template<int SPLIT>
__global__ __launch_bounds__(256, 3) void k_mgemm(
        const u16* __restrict__ Ahg, const u16* __restrict__ Alg,
        const u16* __restrict__ BTh, const u16* __restrict__ BTl,
        const float* __restrict__ bias, float* __restrict__ C1,
        u16* __restrict__ C2b,
        u16* __restrict__ Oh, u16* __restrict__ Ol, int M) {
    __shared__ u16 sAh[64 * 128], sBh[64 * 128], sBl[64 * 128];
    int m0 = blockIdx.y * 64;
    int t = threadIdx.x;
    int lane = t & 63;
    int wm = (t >> 6) & 1;
    int wn = t >> 7;
    int fm = lane & 15;
    int q8 = (lane >> 4) * 8;

    // preload A-lo fragments into registers (8 x 16B per lane).
    short8 fal[4][2];
    #pragma unroll
    for (int i = 0; i < 2; ++i) {
        const u16* p = Alg + (size_t)(m0 + wm * 32 + i * 16 + fm) * 128 + q8;
        #pragma unroll
        for (int kk = 0; kk < 4; ++kk)
            fal[kk][i] = *(const short8*)(p + kk * 32);
    }

    // stage A-hi once, swizzled: chunk c -> c ^ (row & 15)
    #pragma unroll
    for (int i = 0; i < 4; ++i) {
        int c = t + 256 * i;
        int row = c >> 4, ch = c & 15;
        int gm = m0 + row;
        short8 va = {0, 0, 0, 0, 0, 0, 0, 0};
        if (gm < M) va = *(const short8*)&Ahg[gm * 128 + ch * 8];
        *(short8*)&sAh[row * 128 + ((ch ^ (row & 15)) << 3)] = va;
    }

    int cq = q8 >> 3;   // quarter (0..3)

    for (int bb = 0; bb < 2; ++bb) {
        int n0 = (blockIdx.x * 2 + bb) * 64;
        __syncthreads();   // protect sBh/sBl overwrite (covers sAh on bb=0)
        #pragma unroll
        for (int i = 0; i < 4; ++i) {
            int c = t + 256 * i;
            int row = c >> 4, ch = c & 15;
            int gn = n0 + row;
            int d = row * 128 + ((ch ^ (row & 15)) << 3);
            *(short8*)&sBh[d] = *(const short8*)&BTh[gn * 128 + ch * 8];
            *(short8*)&sBl[d] = *(const short8*)&BTl[gn * 128 + ch * 8];
        }
        __syncthreads();

        float4v zz = {0.f, 0.f, 0.f, 0.f};
        float4v acc[2][2];
        acc[0][0] = zz; acc[0][1] = zz; acc[1][0] = zz; acc[1][1] = zz;

        #pragma unroll
        for (int k0 = 0; k0 < 128; k0 += 32) {
            int cl = (k0 >> 3) + cq;        // logical chunk
            int sw = (cl ^ fm) << 3;        // swizzled chunk offset (row&15 == fm)
            short8 fah[2], fbh[2], fbl[2];
            #pragma unroll
            for (int i = 0; i < 2; ++i) {
                int mr = wm * 32 + i * 16 + fm;
                fah[i] = *(const short8*)&sAh[mr * 128 + sw];
                int nr = wn * 32 + i * 16 + fm;
                fbh[i] = *(const short8*)&sBh[nr * 128 + sw];
                fbl[i] = *(const short8*)&sBl[nr * 128 + sw];
            }
            #pragma unroll
            for (int i = 0; i < 2; ++i)
                #pragma unroll
                for (int j = 0; j < 2; ++j) {
                    acc[i][j] = __builtin_amdgcn_mfma_f32_16x16x32_bf16(fah[i], fbh[j], acc[i][j], 0, 0, 0);
                    acc[i][j] = __builtin_amdgcn_mfma_f32_16x16x32_bf16(fah[i], fbl[j], acc[i][j], 0, 0, 0);
                    acc[i][j] = __builtin_amdgcn_mfma_f32_16x16x32_bf16(fal[k0 >> 5][i], fbh[j], acc[i][j], 0, 0, 0);
                }
        }

        // epilogue: C/D layout col=lane&15, row=(lane>>4)*4+reg  [m89]
        #pragma unroll
        for (int i = 0; i < 2; ++i) {
            #pragma unroll
            for (int j = 0; j < 2; ++j) {
                int gn = n0 + wn * 32 + j * 16 + fm;
                float bv = bias[gn];
                #pragma unroll
                for (int r = 0; r < 4; ++r) {
                    int gm = m0 + wm * 32 + i * 16 + (lane >> 4) * 4 + r;
                    if (gm < M) {
                        float v = acc[i][j][r] + bv;
                        if (SPLIT) {
                            u16 h = f2bf(v);
                            Oh[gm * 128 + gn] = h;
                            Ol[gm * 128 + gn] = f2bf(v - bf2f(h));
                        } else if (n0 < 512) {
                            C1[gm * 512 + gn] = v;           // xl fp32
                        } else {
                            C2b[gm * 512 + gn - 512] = f2bf(v);  // xr bf16
                        }
                    }
                }
            }
        }
    }
}

// ---------- fused per-node GATv2: one wave per node (R7/R10/R13 best-measured) ----------
// block = 4 nodes; lane l: head l>>4, dims l*8..l*8+7; 16-lane logit butterfly.
// DO NOT TOUCH the edge loop: R8 (2-edge unroll) and R9 (persistent waves)
// both regressed; this shape measures 62.3-63.1 us. xr now bf16.

__global__ __launch_bounds__(256) void k_gat(
        const int* __restrict__ rowptr, const int* __restrict__ srcs,
        const float* __restrict__ fa0, const float* __restrict__ fa1,
        const float* __restrict__ xl, const u16* __restrict__ xr,
        const float* __restrict__ We, const float* __restrict__ att,
        const float* __restrict__ bias_out,
        u16* __restrict__ Oh, u16* __restrict__ Ol,
        float* __restrict__ outp, int last) {
    int n = blockIdx.x * 4 + (threadIdx.x >> 6);
    if (n >= NN) return;
    int l = threadIdx.x & 63;
    int d0 = l * 8;
    float xrv[8], we0[8], we1[8], atv[8];
    {
        ushort8 u = *reinterpret_cast<const ushort8*>(&xr[(size_t)n * 512 + d0]);
        #pragma unroll
        for (int k = 0; k < 8; ++k) xrv[k] = bf2f(u[k]);
        float4 a = *reinterpret_cast<const float4*>(&We[d0]);
        float4 b = *reinterpret_cast<const float4*>(&We[d0 + 4]);
        we0[0]=a.x; we0[1]=a.y; we0[2]=a.z; we0[3]=a.w;
        we0[4]=b.x; we0[5]=b.y; we0[6]=b.z; we0[7]=b.w;
        a = *reinterpret_cast<const float4*>(&We[512 + d0]);
        b = *reinterpret_cast<const float4*>(&We[512 + d0 + 4]);
        we1[0]=a.x; we1[1]=a.y; we1[2]=a.z; we1[3]=a.w;
        we1[4]=b.x; we1[5]=b.y; we1[6]=b.z; we1[7]=b.w;
        a = *reinterpret_cast<const float4*>(&att[d0]);
        b = *reinterpret_cast<const float4*>(&att[d0 + 4]);
        atv[0]=a.x; atv[1]=a.y; atv[2]=a.z; atv[3]=a.w;
        atv[4]=b.x; atv[5]=b.y; atv[6]=b.z; atv[7]=b.w;
    }
    int b0 = rowptr[n], b1 = rowptr[n + 1];
    float acc[8] = {0.f,0.f,0.f,0.f,0.f,0.f,0.f,0.f};
    float den = 0.f;
    int sNext = srcs[b0];
    for (int e = b0; e < b1; ++e) {
        int s = sNext;
        if (e + 1 < b1) sNext = srcs[e + 1];   // prefetch next gather address
        float f0 = fa0[e], f1 = fa1[e];
        const float* xlp = &xl[(size_t)s * 512 + d0];
        float4 a = *reinterpret_cast<const float4*>(xlp);
        float4 b = *reinterpret_cast<const float4*>(xlp + 4);
        float xv[8] = {a.x, a.y, a.z, a.w, b.x, b.y, b.z, b.w};
        float p = 0.f;
        #pragma unroll
        for (int k = 0; k < 8; ++k) {
            float v = xv[k] + xrv[k] + f0 * we0[k] + f1 * we1[k];
            v = v > 0.f ? v : 0.2f * v;
            p += v * atv[k];
        }
        p += __shfl_xor(p, 1, 64);
        p += __shfl_xor(p, 2, 64);
        p += __shfl_xor(p, 4, 64);
        p += __shfl_xor(p, 8, 64);
        float wt = __expf(p);    // |p| small by construction
        den += wt;
        #pragma unroll
        for (int k = 0; k < 8; ++k) acc[k] += wt * xv[k];
    }
    // per-head normalize (den identical across the 16 lanes of a head)
    float inv = 1.f / den;
    float val[8];
    #pragma unroll
    for (int k = 0; k < 8; ++k) {
        float v = acc[k] * inv;
        v += __shfl_xor(v, 16, 64);   // sum heads
        v += __shfl_xor(v, 32, 64);
        val[k] = v;
    }
    if (l < 16) {
        #pragma unroll
        for (int k = 0; k < 8; ++k) {
            float v = val[k] * 0.25f + bias_out[d0 + k];
            v = v > 0.f ? v : 0.01f * v;
            val[k] = v;
        }
        if (last) {
            #pragma unroll
            for (int k = 0; k < 8; ++k) outp[n * 128 + d0 + k] = val[k];
        } else {
            #pragma unroll
            for (int k = 0; k < 8; ++k) {
                u16 hv = f2bf(val[k]);
                Oh[n * 128 + d0 + k] = hv;
                Ol[n * 128 + d0 + k] = f2bf(val[k] - bf2f(hv));
            }
        }
    }
}

// ---------- launch ----------

extern "C" void kernel_launch(void* const* d_in, const int* in_sizes, int n_in,
                              void* d_out, int out_size, void* d_ws, size_t ws_size,
                              hipStream_t stream) {
    size_t o = 0;
    auto alloc = [&](size_t bytes) { size_t cur = o; o += (bytes + 255) & ~(size_t)255; return cur; };
    size_t off_cnt    = alloc((size_t)NN * 4);
    size_t off_fillc  = alloc((size_t)NN * 4);
    size_t off_easum  = alloc((size_t)NN * 2 * 4);
    size_t off_rowptr = alloc((size_t)(NN + 1) * 4);
    size_t off_srcs   = alloc((size_t)EF * 4);
    size_t off_fa0    = alloc((size_t)EF * 4);
    size_t off_fa1    = alloc((size_t)EF * 4);
    size_t off_axh    = alloc((size_t)NN * DD * 2);
    size_t off_axl    = alloc((size_t)NN * DD * 2);
    size_t off_ah     = alloc((size_t)NN * DD * 2);
    size_t off_al     = alloc((size_t)NN * DD * 2);
    size_t off_xl     = alloc((size_t)NN * 512 * 4);
    size_t off_xr     = alloc((size_t)NN * 512 * 2);   // bf16 now
    size_t off_w2th   = alloc((size_t)1024 * 128 * 2);
    size_t off_w2tl   = alloc((size_t)1024 * 128 * 2);
    size_t off_wfth   = alloc((size_t)128 * 128 * 2);
    size_t off_wftl   = alloc((size_t)128 * 128 * 2);
    size_t off_bias2  = alloc((size_t)1024 * 4);
    size_t need = o;

    bool ok = (n_in == 12) && d_ws != nullptr && ws_size >= need
           && out_size == NN * DD
           && in_sizes[0] == NN * DD && in_sizes[1] == 2 * NE
           && in_sizes[2] == NE * 2 && in_sizes[3] == 128 * 128
           && in_sizes[5] == 128 * 512 && in_sizes[9] == 2 * 512
           && in_sizes[10] == 4 * 128 && in_sizes[11] == 128;
    if (!ok) {
        k_zero_f<<<(NN * DD + 255) / 256, 256, 0, stream>>>((float*)d_out, NN * DD);
        return;
    }

    const float* x        = (const float*)d_in[0];
    const int*   ei       = (const int*)d_in[1];
    const float* ea       = (const float*)d_in[2];
    const float* Wf       = (const float*)d_in[3];
    const float* bf       = (const float*)d_in[4];
    const float* Wl       = (const float*)d_in[5];
    const float* bl       = (const float*)d_in[6];
    const float* Wr       = (const float*)d_in[7];
    const float* br       = (const float*)d_in[8];
    const float* We       = (const float*)d_in[9];
    const float* att      = (const float*)d_in[10];
    const float* bias_out = (const float*)d_in[11];

    char* base = (char*)d_ws;
    int*   cnt    = (int*)(base + off_cnt);
    int*   fillc  = (int*)(base + off_fillc);
    float* ea_sum = (float*)(base + off_easum);
    int*   rowptr = (int*)(base + off_rowptr);
    int*   srcs   = (int*)(base + off_srcs);
    float* fa0    = (float*)(base + off_fa0);
    float* fa1    = (float*)(base + off_fa1);
    u16*   Axh    = (u16*)(base + off_axh);
    u16*   Axl    = (u16*)(base + off_axl);
    u16*   Ah     = (u16*)(base + off_ah);
    u16*   Al     = (u16*)(base + off_al);
    float* xl     = (float*)(base + off_xl);
    u16*   xr     = (u16*)(base + off_xr);
    u16*   W2Th   = (u16*)(base + off_w2th);
    u16*   W2Tl   = (u16*)(base + off_w2tl);
    u16*   WfTh   = (u16*)(base + off_wfth);
    u16*   WfTl   = (u16*)(base + off_wftl);
    float* bias2  = (float*)(base + off_bias2);

    int zero_ints = (int)((off_easum + (size_t)NN * 2 * 4 - off_cnt) / 4);
    k_zero_i<<<(zero_ints + 255) / 256, 256, 0, stream>>>(cnt, zero_ints);

    int packb = (NPA + NPW + 255) / 256;
    k_degpack<<<DEGB + packb, 256, 0, stream>>>(ei, ea, x, Wl, Wr, bl, br, Wf,
                                                cnt, ea_sum, Axh, Axl,
                                                W2Th, W2Tl, WfTh, WfTl, bias2);
    k_scan<<<1, 1024, 0, stream>>>(cnt, rowptr);
    k_fill<<<(NE + NN + 255) / 256, 256, 0, stream>>>(ei, ea, rowptr, fillc,
                                                      cnt, ea_sum, srcs, fa0, fa1);

    const int MT = (NN + 63) / 64;   // 313
    // grid: x = band pair (fast), y = m-tile
    k_mgemm<1><<<dim3(1, MT), 256, 0, stream>>>(Axh, Axl, WfTh, WfTl,
                                                bf, nullptr, nullptr, Ah, Al, NN);

    for (int layer = 0; layer < 3; ++layer) {
        k_mgemm<0><<<dim3(8, MT), 256, 0, stream>>>(Ah, Al, W2Th, W2Tl,
                                                    bias2, xl, xr, nullptr, nullptr, NN);
        int last = (layer == 2);
        k_gat<<<(NN + 3) / 4, 256, 0, stream>>>(rowptr, srcs, fa0, fa1, xl, xr,
                                                We, att, bias_out, Ah, Al,
                                                (float*)d_out, last);
    }
}

// Round 16
// 428.815 us; speedup vs baseline: 1.0819x; 1.0819x over previous
//
#include <hip/hip_runtime.h>
#include <hip/hip_bf16.h>

#define NN 20000
#define NE 160000
#define EF (NE + NN)          // edges + self loops
#define DD 128
#define HH 4
#define NPA (NN * DD)                       // pack_a elements
#define NPW (1024 * 128 + 128 * 128 + 1024) // pack_w elements
#define DEGB ((NE + 255) / 256)             // deg blocks in fused deg+pack
#define NBLK 40                             // scan blocks (512 nodes each)

typedef unsigned short u16;
typedef unsigned int u32;

using short8  = __attribute__((ext_vector_type(8))) short;
using ushort8 = __attribute__((ext_vector_type(8))) unsigned short;
using float4v = __attribute__((ext_vector_type(4))) float;

__device__ __forceinline__ float bf2f(u16 u) {
    union { u32 i; float f; } c;
    c.i = ((u32)u) << 16;
    return c.f;
}
// round-to-nearest-even fp32 -> bf16 bits (finite inputs)
__device__ __forceinline__ u16 f2bf(float f) {
    union { float f; u32 u; } c;
    c.f = f;
    u32 u = c.u;
    u32 r = (u + 0x7fffu + ((u >> 16) & 1u)) >> 16;
    return (u16)r;
}

// ---------- utility ----------

__global__ void k_zero_i(int* __restrict__ p, int n) {
    int i = blockIdx.x * blockDim.x + threadIdx.x;
    if (i < n) p[i] = 0;
}

__global__ void k_zero_f(float* __restrict__ p, int n) {
    int i = blockIdx.x * blockDim.x + threadIdx.x;
    if (i < n) p[i] = 0.f;
}

// ---------- fused deg + pack (independent block ranges) ----------

__global__ void k_degpack(const int* __restrict__ ei, const float* __restrict__ ea,
                          const float* __restrict__ x,
                          const float* __restrict__ Wl, const float* __restrict__ Wr,
                          const float* __restrict__ bl, const float* __restrict__ br,
                          const float* __restrict__ Wf,
                          int* __restrict__ cnt, float* __restrict__ ea_sum,
                          u16* __restrict__ Axh, u16* __restrict__ Axl,
                          u16* __restrict__ W2Th, u16* __restrict__ W2Tl,
                          u16* __restrict__ WfTh, u16* __restrict__ WfTl,
                          float* __restrict__ bias2) {
    int gb = blockIdx.x;
    if (gb < DEGB) {
        int e = gb * 256 + threadIdx.x;
        if (e >= NE) return;
        int t = ei[NE + e];
        atomicAdd(&cnt[t], 1);
        atomicAdd(&ea_sum[t * 2 + 0], ea[e * 2 + 0]);
        atomicAdd(&ea_sum[t * 2 + 1], ea[e * 2 + 1]);
        return;
    }
    int i = (gb - DEGB) * 256 + threadIdx.x;
    if (i < NPA) {
        float a = x[i];
        u16 h = f2bf(a);
        Axh[i] = h;
        Axl[i] = f2bf(a - bf2f(h));
        return;
    }
    i -= NPA;
    if (i < 1024 * 128) {
        int n = i >> 7, k = i & 127;
        float w = (n < 512) ? Wl[k * 512 + n] : Wr[k * 512 + (n - 512)];
        u16 h = f2bf(w);
        W2Th[n * 128 + k] = h;
        W2Tl[n * 128 + k] = f2bf(w - bf2f(h));
    } else if (i < 1024 * 128 + 128 * 128) {
        int u = i - 1024 * 128;
        int n = u >> 7, k = u & 127;
        float w = Wf[k * 128 + n];
        u16 h = f2bf(w);
        WfTh[n * 128 + k] = h;
        WfTl[n * 128 + k] = f2bf(w - bf2f(h));
    } else if (i < NPW) {
        int n = i - (1024 * 128 + 128 * 128);
        bias2[n] = (n < 512) ? bl[n] : br[n - 512];
    }
}

// ---------- parallel scan (R12-verified pair) ----------
// (A) per-512-block local inclusive scan; (C) every wave re-scans the 40
// block sums in-register, adds its block offset.

__global__ __launch_bounds__(512) void k_scan_a(const int* __restrict__ cnt,
                                                int* __restrict__ rowptr,
                                                int* __restrict__ bsum) {
    __shared__ int ws[8];
    int tid = threadIdx.x;
    int i = blockIdx.x * 512 + tid;
    int l = tid & 63, w = tid >> 6;
    int v = (i < NN) ? (cnt[i] + 1) : 0;
    #pragma unroll
    for (int off = 1; off < 64; off <<= 1) {
        int u = __shfl_up(v, off, 64);
        if (l >= off) v += u;
    }
    if (l == 63) ws[w] = v;
    __syncthreads();
    if (w == 0) {
        int s = (l < 8) ? ws[l] : 0;
        #pragma unroll
        for (int off = 1; off < 8; off <<= 1) {
            int u = __shfl_up(s, off, 64);
            if (l >= off) s += u;
        }
        if (l < 8) ws[l] = s;    // inclusive wave sums
    }
    __syncthreads();
    v += (w > 0) ? ws[w - 1] : 0;
    if (i < NN) rowptr[i + 1] = v;   // block-local inclusive
    if (tid == 511) bsum[blockIdx.x] = v;
}

__global__ void k_scan_c(int* __restrict__ rowptr, const int* __restrict__ bsum) {
    int l = threadIdx.x & 63;
    int v = (l < NBLK) ? bsum[l] : 0;
    #pragma unroll
    for (int off = 1; off < 64; off <<= 1) {
        int u = __shfl_up(v, off, 64);
        if (l >= off) v += u;
    }
    int i = blockIdx.x * blockDim.x + threadIdx.x;
    int j = i >> 9;
    int off = (j > 0) ? __shfl(v, j - 1, 64) : 0;
    if (i < NN) rowptr[i + 1] += off;
    if (i == 0) rowptr[0] = 0;
}

// ---------- fused fill + self-loop ----------

__global__ void k_fill(const int* __restrict__ ei, const float* __restrict__ ea,
                       const int* __restrict__ rowptr, int* __restrict__ fillc,
                       const int* __restrict__ cnt, const float* __restrict__ ea_sum,
                       int* __restrict__ srcs,
                       float* __restrict__ fa0, float* __restrict__ fa1) {
    int e = blockIdx.x * blockDim.x + threadIdx.x;
    if (e < NE) {
        int s = ei[e], t = ei[NE + e];
        int pos = atomicAdd(&fillc[t], 1);
        int slot = rowptr[t] + pos;
        srcs[slot] = s;
        fa0[slot] = ea[e * 2];
        fa1[slot] = ea[e * 2 + 1];
    } else if (e < NE + NN) {
        int n = e - NE;
        int slot = rowptr[n + 1] - 1;   // self-loop is last slot
        srcs[slot] = n;
        float c = fmaxf((float)cnt[n], 1.f);
        fa0[slot] = ea_sum[n * 2 + 0] / c;
        fa1[slot] = ea_sum[n * 2 + 1] / c;
    }
}

// ---------- split-bf16 MFMA GEMM ----------
// XOR-swizzled LDS (chunk c of row r at c^(r&15)), 48 KB -> 3 blocks/CU.
// 3-term split: ah*bh + ah*bl + al*bh; A-lo in registers; NB bands per block
// (A-staging + register preload amortized over NB B-stages; R13->R14 2-band
// change measured -9.6 us, extending to 4).
// xr output (bands n0>=512) written bf16 (R15-verified: absmax unchanged).

template<int SPLIT, int NB>
__global__ __launch_bounds__(256, 3) void k_mgemm(
        const u16* __restrict__ Ahg, const u16* __restrict__ Alg,
        const u16* __restrict__ BTh, const u16* __restrict__ BTl,
        const float* __restrict__ bias, float* __restrict__ C1,
        u16* __restrict__ C2b,
        u16* __restrict__ Oh, u16* __restrict__ Ol, int M) {
    __shared__ u16 sAh[64 * 128], sBh[64 * 128], sBl[64 * 128];
    int m0 = blockIdx.y * 64;
    int t = threadIdx.x;
    int lane = t & 63;
    int wm = (t >> 6) & 1;
    int wn = t >> 7;
    int fm = lane & 15;
    int q8 = (lane >> 4) * 8;

    // preload A-lo fragments into registers (8 x 16B per lane).
    short8 fal[4][2];
    #pragma unroll
    for (int i = 0; i < 2; ++i) {
        const u16* p = Alg + (size_t)(m0 + wm * 32 + i * 16 + fm) * 128 + q8;
        #pragma unroll
        for (int kk = 0; kk < 4; ++kk)
            fal[kk][i] = *(const short8*)(p + kk * 32);
    }

    // stage A-hi once, swizzled: chunk c -> c ^ (row & 15)
    #pragma unroll
    for (int i = 0; i < 4; ++i) {
        int c = t + 256 * i;
        int row = c >> 4, ch = c & 15;
        int gm = m0 + row;
        short8 va = {0, 0, 0, 0, 0, 0, 0, 0};
        if (gm < M) va = *(const short8*)&Ahg[gm * 128 + ch * 8];
        *(short8*)&sAh[row * 128 + ((ch ^ (row & 15)) << 3)] = va;
    }

    int cq = q8 >> 3;   // quarter (0..3)

    for (int bb = 0; bb < NB; ++bb) {
        int n0 = (blockIdx.x * NB + bb) * 64;
        __syncthreads();   // protect sBh/sBl overwrite (covers sAh on bb=0)
        #pragma unroll
        for (int i = 0; i < 4; ++i) {
            int c = t + 256 * i;
            int row = c >> 4, ch = c & 15;
            int gn = n0 + row;
            int d = row * 128 + ((ch ^ (row & 15)) << 3);
            *(short8*)&sBh[d] = *(const short8*)&BTh[gn * 128 + ch * 8];
            *(short8*)&sBl[d] = *(const short8*)&BTl[gn * 128 + ch * 8];
        }
        __syncthreads();

        float4v zz = {0.f, 0.f, 0.f, 0.f};
        float4v acc[2][2];
        acc[0][0] = zz; acc[0][1] = zz; acc[1][0] = zz; acc[1][1] = zz;

        #pragma unroll
        for (int k0 = 0; k0 < 128; k0 += 32) {
            int cl = (k0 >> 3) + cq;        // logical chunk
            int sw = (cl ^ fm) << 3;        // swizzled chunk offset
            short8 fah[2], fbh[2], fbl[2];
            #pragma unroll
            for (int i = 0; i < 2; ++i) {
                int mr = wm * 32 + i * 16 + fm;
                fah[i] = *(const short8*)&sAh[mr * 128 + sw];
                int nr = wn * 32 + i * 16 + fm;
                fbh[i] = *(const short8*)&sBh[nr * 128 + sw];
                fbl[i] = *(const short8*)&sBl[nr * 128 + sw];
            }
            #pragma unroll
            for (int i = 0; i < 2; ++i)
                #pragma unroll
                for (int j = 0; j < 2; ++j) {
                    acc[i][j] = __builtin_amdgcn_mfma_f32_16x16x32_bf16(fah[i], fbh[j], acc[i][j], 0, 0, 0);
                    acc[i][j] = __builtin_amdgcn_mfma_f32_16x16x32_bf16(fah[i], fbl[j], acc[i][j], 0, 0, 0);
                    acc[i][j] = __builtin_amdgcn_mfma_f32_16x16x32_bf16(fal[k0 >> 5][i], fbh[j], acc[i][j], 0, 0, 0);
                }
        }

        // epilogue: C/D layout col=lane&15, row=(lane>>4)*4+reg  [m89]
        #pragma unroll
        for (int i = 0; i < 2; ++i) {
            #pragma unroll
            for (int j = 0; j < 2; ++j) {
                int gn = n0 + wn * 32 + j * 16 + fm;
                float bv = bias[gn];
                #pragma unroll
                for (int r = 0; r < 4; ++r) {
                    int gm = m0 + wm * 32 + i * 16 + (lane >> 4) * 4 + r;
                    if (gm < M) {
                        float v = acc[i][j][r] + bv;
                        if (SPLIT) {
                            u16 h = f2bf(v);
                            Oh[gm * 128 + gn] = h;
                            Ol[gm * 128 + gn] = f2bf(v - bf2f(h));
                        } else if (n0 < 512) {
                            C1[gm * 512 + gn] = v;           // xl fp32
                        } else {
                            C2b[gm * 512 + gn - 512] = f2bf(v);  // xr bf16
                        }
                    }
                }
            }
        }
    }
}

// ---------- fused per-node GATv2: one wave per node (R7/R10/R13 best-measured) ----------
// block = 4 nodes; lane l: head l>>4, dims l*8..l*8+7; 16-lane logit butterfly.
// DO NOT TOUCH the edge loop: R8 (2-edge unroll) and R9 (persistent waves)
// both regressed; this shape measures 59.6-59.8 us with bf16 xr.

__global__ __launch_bounds__(256) void k_gat(
        const int* __restrict__ rowptr, const int* __restrict__ srcs,
        const float* __restrict__ fa0, const float* __restrict__ fa1,
        const float* __restrict__ xl, const u16* __restrict__ xr,
        const float* __restrict__ We, const float* __restrict__ att,
        const float* __restrict__ bias_out,
        u16* __restrict__ Oh, u16* __restrict__ Ol,
        float* __restrict__ outp, int last) {
    int n = blockIdx.x * 4 + (threadIdx.x >> 6);
    if (n >= NN) return;
    int l = threadIdx.x & 63;
    int d0 = l * 8;
    float xrv[8], we0[8], we1[8], atv[8];
    {
        ushort8 u = *reinterpret_cast<const ushort8*>(&xr[(size_t)n * 512 + d0]);
        #pragma unroll
        for (int k = 0; k < 8; ++k) xrv[k] = bf2f(u[k]);
        float4 a = *reinterpret_cast<const float4*>(&We[d0]);
        float4 b = *reinterpret_cast<const float4*>(&We[d0 + 4]);
        we0[0]=a.x; we0[1]=a.y; we0[2]=a.z; we0[3]=a.w;
        we0[4]=b.x; we0[5]=b.y; we0[6]=b.z; we0[7]=b.w;
        a = *reinterpret_cast<const float4*>(&We[512 + d0]);
        b = *reinterpret_cast<const float4*>(&We[512 + d0 + 4]);
        we1[0]=a.x; we1[1]=a.y; we1[2]=a.z; we1[3]=a.w;
        we1[4]=b.x; we1[5]=b.y; we1[6]=b.z; we1[7]=b.w;
        a = *reinterpret_cast<const float4*>(&att[d0]);
        b = *reinterpret_cast<const float4*>(&att[d0 + 4]);
        atv[0]=a.x; atv[1]=a.y; atv[2]=a.z; atv[3]=a.w;
        atv[4]=b.x; atv[5]=b.y; atv[6]=b.z; atv[7]=b.w;
    }
    int b0 = rowptr[n], b1 = rowptr[n + 1];
    float acc[8] = {0.f,0.f,0.f,0.f,0.f,0.f,0.f,0.f};
    float den = 0.f;
    int sNext = srcs[b0];
    for (int e = b0; e < b1; ++e) {
        int s = sNext;
        if (e + 1 < b1) sNext = srcs[e + 1];   // prefetch next gather address
        float f0 = fa0[e], f1 = fa1[e];
        const float* xlp = &xl[(size_t)s * 512 + d0];
        float4 a = *reinterpret_cast<const float4*>(xlp);
        float4 b = *reinterpret_cast<const float4*>(xlp + 4);
        float xv[8] = {a.x, a.y, a.z, a.w, b.x, b.y, b.z, b.w};
        float p = 0.f;
        #pragma unroll
        for (int k = 0; k < 8; ++k) {
            float v = xv[k] + xrv[k] + f0 * we0[k] + f1 * we1[k];
            v = v > 0.f ? v : 0.2f * v;
            p += v * atv[k];
        }
        p += __shfl_xor(p, 1, 64);
        p += __shfl_xor(p, 2, 64);
        p += __shfl_xor(p, 4, 64);
        p += __shfl_xor(p, 8, 64);
        float wt = __expf(p);    // |p| small by construction
        den += wt;
        #pragma unroll
        for (int k = 0; k < 8; ++k) acc[k] += wt * xv[k];
    }
    // per-head normalize (den identical across the 16 lanes of a head)
    float inv = 1.f / den;
    float val[8];
    #pragma unroll
    for (int k = 0; k < 8; ++k) {
        float v = acc[k] * inv;
        v += __shfl_xor(v, 16, 64);   // sum heads
        v += __shfl_xor(v, 32, 64);
        val[k] = v;
    }
    if (l < 16) {
        #pragma unroll
        for (int k = 0; k < 8; ++k) {
            float v = val[k] * 0.25f + bias_out[d0 + k];
            v = v > 0.f ? v : 0.01f * v;
            val[k] = v;
        }
        if (last) {
            #pragma unroll
            for (int k = 0; k < 8; ++k) outp[n * 128 + d0 + k] = val[k];
        } else {
            #pragma unroll
            for (int k = 0; k < 8; ++k) {
                u16 hv = f2bf(val[k]);
                Oh[n * 128 + d0 + k] = hv;
                Ol[n * 128 + d0 + k] = f2bf(val[k] - bf2f(hv));
            }
        }
    }
}

// ---------- launch ----------

extern "C" void kernel_launch(void* const* d_in, const int* in_sizes, int n_in,
                              void* d_out, int out_size, void* d_ws, size_t ws_size,
                              hipStream_t stream) {
    size_t o = 0;
    auto alloc = [&](size_t bytes) { size_t cur = o; o += (bytes + 255) & ~(size_t)255; return cur; };
    size_t off_cnt    = alloc((size_t)NN * 4);
    size_t off_fillc  = alloc((size_t)NN * 4);
    size_t off_easum  = alloc((size_t)NN * 2 * 4);
    size_t off_rowptr = alloc((size_t)(NN + 1) * 4);
    size_t off_bsum   = alloc((size_t)NBLK * 4);
    size_t off_srcs   = alloc((size_t)EF * 4);
    size_t off_fa0    = alloc((size_t)EF * 4);
    size_t off_fa1    = alloc((size_t)EF * 4);
    size_t off_axh    = alloc((size_t)NN * DD * 2);
    size_t off_axl    = alloc((size_t)NN * DD * 2);
    size_t off_ah     = alloc((size_t)NN * DD * 2);
    size_t off_al     = alloc((size_t)NN * DD * 2);
    size_t off_xl     = alloc((size_t)NN * 512 * 4);
    size_t off_xr     = alloc((size_t)NN * 512 * 2);   // bf16
    size_t off_w2th   = alloc((size_t)1024 * 128 * 2);
    size_t off_w2tl   = alloc((size_t)1024 * 128 * 2);
    size_t off_wfth   = alloc((size_t)128 * 128 * 2);
    size_t off_wftl   = alloc((size_t)128 * 128 * 2);
    size_t off_bias2  = alloc((size_t)1024 * 4);
    size_t need = o;

    bool ok = (n_in == 12) && d_ws != nullptr && ws_size >= need
           && out_size == NN * DD
           && in_sizes[0] == NN * DD && in_sizes[1] == 2 * NE
           && in_sizes[2] == NE * 2 && in_sizes[3] == 128 * 128
           && in_sizes[5] == 128 * 512 && in_sizes[9] == 2 * 512
           && in_sizes[10] == 4 * 128 && in_sizes[11] == 128;
    if (!ok) {
        k_zero_f<<<(NN * DD + 255) / 256, 256, 0, stream>>>((float*)d_out, NN * DD);
        return;
    }

    const float* x        = (const float*)d_in[0];
    const int*   ei       = (const int*)d_in[1];
    const float* ea       = (const float*)d_in[2];
    const float* Wf       = (const float*)d_in[3];
    const float* bf       = (const float*)d_in[4];
    const float* Wl       = (const float*)d_in[5];
    const float* bl       = (const float*)d_in[6];
    const float* Wr       = (const float*)d_in[7];
    const float* br       = (const float*)d_in[8];
    const float* We       = (const float*)d_in[9];
    const float* att      = (const float*)d_in[10];
    const float* bias_out = (const float*)d_in[11];

    char* base = (char*)d_ws;
    int*   cnt    = (int*)(base + off_cnt);
    int*   fillc  = (int*)(base + off_fillc);
    float* ea_sum = (float*)(base + off_easum);
    int*   rowptr = (int*)(base + off_rowptr);
    int*   bsum   = (int*)(base + off_bsum);
    int*   srcs   = (int*)(base + off_srcs);
    float* fa0    = (float*)(base + off_fa0);
    float* fa1    = (float*)(base + off_fa1);
    u16*   Axh    = (u16*)(base + off_axh);
    u16*   Axl    = (u16*)(base + off_axl);
    u16*   Ah     = (u16*)(base + off_ah);
    u16*   Al     = (u16*)(base + off_al);
    float* xl     = (float*)(base + off_xl);
    u16*   xr     = (u16*)(base + off_xr);
    u16*   W2Th   = (u16*)(base + off_w2th);
    u16*   W2Tl   = (u16*)(base + off_w2tl);
    u16*   WfTh   = (u16*)(base + off_wfth);
    u16*   WfTl   = (u16*)(base + off_wftl);
    float* bias2  = (float*)(base + off_bias2);

    int zero_ints = (int)((off_easum + (size_t)NN * 2 * 4 - off_cnt) / 4);
    k_zero_i<<<(zero_ints + 255) / 256, 256, 0, stream>>>(cnt, zero_ints);

    int packb = (NPA + NPW + 255) / 256;
    k_degpack<<<DEGB + packb, 256, 0, stream>>>(ei, ea, x, Wl, Wr, bl, br, Wf,
                                                cnt, ea_sum, Axh, Axl,
                                                W2Th, W2Tl, WfTh, WfTl, bias2);
    k_scan_a<<<NBLK, 512, 0, stream>>>(cnt, rowptr, bsum);
    k_scan_c<<<(NN + 255) / 256, 256, 0, stream>>>(rowptr, bsum);
    k_fill<<<(NE + NN + 255) / 256, 256, 0, stream>>>(ei, ea, rowptr, fillc,
                                                      cnt, ea_sum, srcs, fa0, fa1);

    const int MT = (NN + 63) / 64;   // 313
    // grid: x = band group (fast), y = m-tile
    k_mgemm<1, 2><<<dim3(1, MT), 256, 0, stream>>>(Axh, Axl, WfTh, WfTl,
                                                   bf, nullptr, nullptr, Ah, Al, NN);

    for (int layer = 0; layer < 3; ++layer) {
        k_mgemm<0, 4><<<dim3(4, MT), 256, 0, stream>>>(Ah, Al, W2Th, W2Tl,
                                                       bias2, xl, xr, nullptr, nullptr, NN);
        int last = (layer == 2);
        k_gat<<<(NN + 3) / 4, 256, 0, stream>>>(rowptr, srcs, fa0, fa1, xl, xr,
                                                We, att, bias_out, Ah, Al,
                                                (float*)d_out, last);
    }
}

// Round 17
// 412.226 us; speedup vs baseline: 1.1255x; 1.0402x over previous
//
#include <hip/hip_runtime.h>
#include <hip/hip_bf16.h>

#define NN 20000
#define NE 160000
#define EF (NE + NN)          // edges + self loops
#define DD 128
#define HH 4
#define NPA (NN * DD)                       // pack_a elements
#define NPW (1024 * 128 + 128 * 128 + 1024) // pack_w elements
#define DEGB ((NE + 255) / 256)             // deg blocks in fused deg+pack
#define NBLK 40                             // scan blocks (512 nodes each)

typedef unsigned short u16;
typedef unsigned int u32;

using short8  = __attribute__((ext_vector_type(8))) short;
using ushort8 = __attribute__((ext_vector_type(8))) unsigned short;
using float4v = __attribute__((ext_vector_type(4))) float;

__device__ __forceinline__ float bf2f(u16 u) {
    union { u32 i; float f; } c;
    c.i = ((u32)u) << 16;
    return c.f;
}
// round-to-nearest-even fp32 -> bf16 bits (finite inputs)
__device__ __forceinline__ u16 f2bf(float f) {
    union { float f; u32 u; } c;
    c.f = f;
    u32 u = c.u;
    u32 r = (u + 0x7fffu + ((u >> 16) & 1u)) >> 16;
    return (u16)r;
}

// ---------- utility ----------

__global__ void k_zero_i(int* __restrict__ p, int n) {
    int i = blockIdx.x * blockDim.x + threadIdx.x;
    if (i < n) p[i] = 0;
}

__global__ void k_zero_f(float* __restrict__ p, int n) {
    int i = blockIdx.x * blockDim.x + threadIdx.x;
    if (i < n) p[i] = 0.f;
}

// ---------- fused deg + pack (independent block ranges) ----------

__global__ void k_degpack(const int* __restrict__ ei, const float* __restrict__ ea,
                          const float* __restrict__ x,
                          const float* __restrict__ Wl, const float* __restrict__ Wr,
                          const float* __restrict__ bl, const float* __restrict__ br,
                          const float* __restrict__ Wf,
                          int* __restrict__ cnt, float* __restrict__ ea_sum,
                          u16* __restrict__ Axh, u16* __restrict__ Axl,
                          u16* __restrict__ W2Th, u16* __restrict__ W2Tl,
                          u16* __restrict__ WfTh, u16* __restrict__ WfTl,
                          float* __restrict__ bias2) {
    int gb = blockIdx.x;
    if (gb < DEGB) {
        int e = gb * 256 + threadIdx.x;
        if (e >= NE) return;
        int t = ei[NE + e];
        atomicAdd(&cnt[t], 1);
        atomicAdd(&ea_sum[t * 2 + 0], ea[e * 2 + 0]);
        atomicAdd(&ea_sum[t * 2 + 1], ea[e * 2 + 1]);
        return;
    }
    int i = (gb - DEGB) * 256 + threadIdx.x;
    if (i < NPA) {
        float a = x[i];
        u16 h = f2bf(a);
        Axh[i] = h;
        Axl[i] = f2bf(a - bf2f(h));
        return;
    }
    i -= NPA;
    if (i < 1024 * 128) {
        int n = i >> 7, k = i & 127;
        float w = (n < 512) ? Wl[k * 512 + n] : Wr[k * 512 + (n - 512)];
        u16 h = f2bf(w);
        W2Th[n * 128 + k] = h;
        W2Tl[n * 128 + k] = f2bf(w - bf2f(h));
    } else if (i < 1024 * 128 + 128 * 128) {
        int u = i - 1024 * 128;
        int n = u >> 7, k = u & 127;
        float w = Wf[k * 128 + n];
        u16 h = f2bf(w);
        WfTh[n * 128 + k] = h;
        WfTl[n * 128 + k] = f2bf(w - bf2f(h));
    } else if (i < NPW) {
        int n = i - (1024 * 128 + 128 * 128);
        bias2[n] = (n < 512) ? bl[n] : br[n - 512];
    }
}

// ---------- parallel scan (R12/R16-verified pair) ----------

__global__ __launch_bounds__(512) void k_scan_a(const int* __restrict__ cnt,
                                                int* __restrict__ rowptr,
                                                int* __restrict__ bsum) {
    __shared__ int ws[8];
    int tid = threadIdx.x;
    int i = blockIdx.x * 512 + tid;
    int l = tid & 63, w = tid >> 6;
    int v = (i < NN) ? (cnt[i] + 1) : 0;
    #pragma unroll
    for (int off = 1; off < 64; off <<= 1) {
        int u = __shfl_up(v, off, 64);
        if (l >= off) v += u;
    }
    if (l == 63) ws[w] = v;
    __syncthreads();
    if (w == 0) {
        int s = (l < 8) ? ws[l] : 0;
        #pragma unroll
        for (int off = 1; off < 8; off <<= 1) {
            int u = __shfl_up(s, off, 64);
            if (l >= off) s += u;
        }
        if (l < 8) ws[l] = s;    // inclusive wave sums
    }
    __syncthreads();
    v += (w > 0) ? ws[w - 1] : 0;
    if (i < NN) rowptr[i + 1] = v;   // block-local inclusive
    if (tid == 511) bsum[blockIdx.x] = v;
}

__global__ void k_scan_c(int* __restrict__ rowptr, const int* __restrict__ bsum) {
    int l = threadIdx.x & 63;
    int v = (l < NBLK) ? bsum[l] : 0;
    #pragma unroll
    for (int off = 1; off < 64; off <<= 1) {
        int u = __shfl_up(v, off, 64);
        if (l >= off) v += u;
    }
    int i = blockIdx.x * blockDim.x + threadIdx.x;
    int j = i >> 9;
    int off = (j > 0) ? __shfl(v, j - 1, 64) : 0;
    if (i < NN) rowptr[i + 1] += off;
    if (i == 0) rowptr[0] = 0;
}

// ---------- fused fill + self-loop ----------

__global__ void k_fill(const int* __restrict__ ei, const float* __restrict__ ea,
                       const int* __restrict__ rowptr, int* __restrict__ fillc,
                       const int* __restrict__ cnt, const float* __restrict__ ea_sum,
                       int* __restrict__ srcs,
                       float* __restrict__ fa0, float* __restrict__ fa1) {
    int e = blockIdx.x * blockDim.x + threadIdx.x;
    if (e < NE) {
        int s = ei[e], t = ei[NE + e];
        int pos = atomicAdd(&fillc[t], 1);
        int slot = rowptr[t] + pos;
        srcs[slot] = s;
        fa0[slot] = ea[e * 2];
        fa1[slot] = ea[e * 2 + 1];
    } else if (e < NE + NN) {
        int n = e - NE;
        int slot = rowptr[n + 1] - 1;   // self-loop is last slot
        srcs[slot] = n;
        float c = fmaxf((float)cnt[n], 1.f);
        fa0[slot] = ea_sum[n * 2 + 0] / c;
        fa1[slot] = ea_sum[n * 2 + 1] / c;
    }
}

// ---------- split-bf16 MFMA GEMM ----------
// XOR-swizzled LDS, 48 KB -> 3 blocks/CU; 3-term split; A-lo in registers;
// NB bands per block (R14 2-band -9.6us, R16 4-band part of -35us; now 8).
// xr bands (n0>=512) written bf16 (R15-verified).

template<int SPLIT, int NB>
__global__ __launch_bounds__(256, 3) void k_mgemm(
        const u16* __restrict__ Ahg, const u16* __restrict__ Alg,
        const u16* __restrict__ BTh, const u16* __restrict__ BTl,
        const float* __restrict__ bias, float* __restrict__ C1,
        u16* __restrict__ C2b,
        u16* __restrict__ Oh, u16* __restrict__ Ol, int M) {
    __shared__ u16 sAh[64 * 128], sBh[64 * 128], sBl[64 * 128];
    int m0 = blockIdx.y * 64;
    int t = threadIdx.x;
    int lane = t & 63;
    int wm = (t >> 6) & 1;
    int wn = t >> 7;
    int fm = lane & 15;
    int q8 = (lane >> 4) * 8;

    // preload A-lo fragments into registers (8 x 16B per lane).
    short8 fal[4][2];
    #pragma unroll
    for (int i = 0; i < 2; ++i) {
        const u16* p = Alg + (size_t)(m0 + wm * 32 + i * 16 + fm) * 128 + q8;
        #pragma unroll
        for (int kk = 0; kk < 4; ++kk)
            fal[kk][i] = *(const short8*)(p + kk * 32);
    }

    // stage A-hi once, swizzled: chunk c -> c ^ (row & 15)
    #pragma unroll
    for (int i = 0; i < 4; ++i) {
        int c = t + 256 * i;
        int row = c >> 4, ch = c & 15;
        int gm = m0 + row;
        short8 va = {0, 0, 0, 0, 0, 0, 0, 0};
        if (gm < M) va = *(const short8*)&Ahg[gm * 128 + ch * 8];
        *(short8*)&sAh[row * 128 + ((ch ^ (row & 15)) << 3)] = va;
    }

    int cq = q8 >> 3;   // quarter (0..3)

    for (int bb = 0; bb < NB; ++bb) {
        int n0 = (blockIdx.x * NB + bb) * 64;
        __syncthreads();   // protect sBh/sBl overwrite (covers sAh on bb=0)
        #pragma unroll
        for (int i = 0; i < 4; ++i) {
            int c = t + 256 * i;
            int row = c >> 4, ch = c & 15;
            int gn = n0 + row;
            int d = row * 128 + ((ch ^ (row & 15)) << 3);
            *(short8*)&sBh[d] = *(const short8*)&BTh[gn * 128 + ch * 8];
            *(short8*)&sBl[d] = *(const short8*)&BTl[gn * 128 + ch * 8];
        }
        __syncthreads();

        float4v zz = {0.f, 0.f, 0.f, 0.f};
        float4v acc[2][2];
        acc[0][0] = zz; acc[0][1] = zz; acc[1][0] = zz; acc[1][1] = zz;

        #pragma unroll
        for (int k0 = 0; k0 < 128; k0 += 32) {
            int cl = (k0 >> 3) + cq;        // logical chunk
            int sw = (cl ^ fm) << 3;        // swizzled chunk offset
            short8 fah[2], fbh[2], fbl[2];
            #pragma unroll
            for (int i = 0; i < 2; ++i) {
                int mr = wm * 32 + i * 16 + fm;
                fah[i] = *(const short8*)&sAh[mr * 128 + sw];
                int nr = wn * 32 + i * 16 + fm;
                fbh[i] = *(const short8*)&sBh[nr * 128 + sw];
                fbl[i] = *(const short8*)&sBl[nr * 128 + sw];
            }
            #pragma unroll
            for (int i = 0; i < 2; ++i)
                #pragma unroll
                for (int j = 0; j < 2; ++j) {
                    acc[i][j] = __builtin_amdgcn_mfma_f32_16x16x32_bf16(fah[i], fbh[j], acc[i][j], 0, 0, 0);
                    acc[i][j] = __builtin_amdgcn_mfma_f32_16x16x32_bf16(fah[i], fbl[j], acc[i][j], 0, 0, 0);
                    acc[i][j] = __builtin_amdgcn_mfma_f32_16x16x32_bf16(fal[k0 >> 5][i], fbh[j], acc[i][j], 0, 0, 0);
                }
        }

        // epilogue: C/D layout col=lane&15, row=(lane>>4)*4+reg  [m89]
        #pragma unroll
        for (int i = 0; i < 2; ++i) {
            #pragma unroll
            for (int j = 0; j < 2; ++j) {
                int gn = n0 + wn * 32 + j * 16 + fm;
                float bv = bias[gn];
                #pragma unroll
                for (int r = 0; r < 4; ++r) {
                    int gm = m0 + wm * 32 + i * 16 + (lane >> 4) * 4 + r;
                    if (gm < M) {
                        float v = acc[i][j][r] + bv;
                        if (SPLIT) {
                            u16 h = f2bf(v);
                            Oh[gm * 128 + gn] = h;
                            Ol[gm * 128 + gn] = f2bf(v - bf2f(h));
                        } else if (n0 < 512) {
                            C1[gm * 512 + gn] = v;           // xl fp32
                        } else {
                            C2b[gm * 512 + gn - 512] = f2bf(v);  // xr bf16
                        }
                    }
                }
            }
        }
    }
}

// ---------- fused per-node GATv2: TWO waves per node (even/odd edge split) ----------
// block = 2 nodes (4 waves); wave pair splits the node's edge list by parity,
// halving the per-wave serial gather chain (k_gat is latency-bound: VALU 46%,
// fetch 3.0 TB/s, occ 37%). Merge via one LDS exchange; normalize AFTER merge
// (odd wave may have 0 edges; self-loop guarantees den>0 combined).
// Edge-loop body identical to the R7/R13 proven shape.

__global__ __launch_bounds__(256) void k_gat(
        const int* __restrict__ rowptr, const int* __restrict__ srcs,
        const float* __restrict__ fa0, const float* __restrict__ fa1,
        const float* __restrict__ xl, const u16* __restrict__ xr,
        const float* __restrict__ We, const float* __restrict__ att,
        const float* __restrict__ bias_out,
        u16* __restrict__ Oh, u16* __restrict__ Ol,
        float* __restrict__ outp, int last) {
    __shared__ float sacc[2][512];
    __shared__ float sden[2][4];
    int wv = threadIdx.x >> 6;
    int pair = wv >> 1;          // node within block
    int half = wv & 1;           // 0: even edges + epilogue, 1: odd edges
    int n = blockIdx.x * 2 + pair;   // NN even, grid = NN/2 -> always < NN
    int l = threadIdx.x & 63;
    int d0 = l * 8;
    float xrv[8], we0[8], we1[8], atv[8];
    {
        ushort8 u = *reinterpret_cast<const ushort8*>(&xr[(size_t)n * 512 + d0]);
        #pragma unroll
        for (int k = 0; k < 8; ++k) xrv[k] = bf2f(u[k]);
        float4 a = *reinterpret_cast<const float4*>(&We[d0]);
        float4 b = *reinterpret_cast<const float4*>(&We[d0 + 4]);
        we0[0]=a.x; we0[1]=a.y; we0[2]=a.z; we0[3]=a.w;
        we0[4]=b.x; we0[5]=b.y; we0[6]=b.z; we0[7]=b.w;
        a = *reinterpret_cast<const float4*>(&We[512 + d0]);
        b = *reinterpret_cast<const float4*>(&We[512 + d0 + 4]);
        we1[0]=a.x; we1[1]=a.y; we1[2]=a.z; we1[3]=a.w;
        we1[4]=b.x; we1[5]=b.y; we1[6]=b.z; we1[7]=b.w;
        a = *reinterpret_cast<const float4*>(&att[d0]);
        b = *reinterpret_cast<const float4*>(&att[d0 + 4]);
        atv[0]=a.x; atv[1]=a.y; atv[2]=a.z; atv[3]=a.w;
        atv[4]=b.x; atv[5]=b.y; atv[6]=b.z; atv[7]=b.w;
    }
    int b0 = rowptr[n], b1 = rowptr[n + 1];
    float acc[8] = {0.f,0.f,0.f,0.f,0.f,0.f,0.f,0.f};
    float den = 0.f;
    int e0 = b0 + half;
    if (e0 < b1) {
        int sNext = srcs[e0];
        for (int e = e0; e < b1; e += 2) {
            int s = sNext;
            if (e + 2 < b1) sNext = srcs[e + 2];   // prefetch next gather address
            float f0 = fa0[e], f1 = fa1[e];
            const float* xlp = &xl[(size_t)s * 512 + d0];
            float4 a = *reinterpret_cast<const float4*>(xlp);
            float4 b = *reinterpret_cast<const float4*>(xlp + 4);
            float xv[8] = {a.x, a.y, a.z, a.w, b.x, b.y, b.z, b.w};
            float p = 0.f;
            #pragma unroll
            for (int k = 0; k < 8; ++k) {
                float v = xv[k] + xrv[k] + f0 * we0[k] + f1 * we1[k];
                v = v > 0.f ? v : 0.2f * v;
                p += v * atv[k];
            }
            p += __shfl_xor(p, 1, 64);
            p += __shfl_xor(p, 2, 64);
            p += __shfl_xor(p, 4, 64);
            p += __shfl_xor(p, 8, 64);
            float wt = __expf(p);    // |p| small by construction
            den += wt;
            #pragma unroll
            for (int k = 0; k < 8; ++k) acc[k] += wt * xv[k];
        }
    }
    // pair merge: odd wave publishes, even wave combines
    if (half == 1) {
        *reinterpret_cast<float4*>(&sacc[pair][d0]) =
            make_float4(acc[0], acc[1], acc[2], acc[3]);
        *reinterpret_cast<float4*>(&sacc[pair][d0 + 4]) =
            make_float4(acc[4], acc[5], acc[6], acc[7]);
        if ((l & 15) == 0) sden[pair][l >> 4] = den;
    }
    __syncthreads();
    if (half == 1) return;
    #pragma unroll
    for (int k = 0; k < 8; ++k) acc[k] += sacc[pair][d0 + k];
    den += sden[pair][l >> 4];
    // per-head normalize (den identical across the 16 lanes of a head)
    float inv = 1.f / den;
    float val[8];
    #pragma unroll
    for (int k = 0; k < 8; ++k) {
        float v = acc[k] * inv;
        v += __shfl_xor(v, 16, 64);   // sum heads
        v += __shfl_xor(v, 32, 64);
        val[k] = v;
    }
    if (l < 16) {
        #pragma unroll
        for (int k = 0; k < 8; ++k) {
            float v = val[k] * 0.25f + bias_out[d0 + k];
            v = v > 0.f ? v : 0.01f * v;
            val[k] = v;
        }
        if (last) {
            #pragma unroll
            for (int k = 0; k < 8; ++k) outp[n * 128 + d0 + k] = val[k];
        } else {
            #pragma unroll
            for (int k = 0; k < 8; ++k) {
                u16 hv = f2bf(val[k]);
                Oh[n * 128 + d0 + k] = hv;
                Ol[n * 128 + d0 + k] = f2bf(val[k] - bf2f(hv));
            }
        }
    }
}

// ---------- launch ----------

extern "C" void kernel_launch(void* const* d_in, const int* in_sizes, int n_in,
                              void* d_out, int out_size, void* d_ws, size_t ws_size,
                              hipStream_t stream) {
    size_t o = 0;
    auto alloc = [&](size_t bytes) { size_t cur = o; o += (bytes + 255) & ~(size_t)255; return cur; };
    size_t off_cnt    = alloc((size_t)NN * 4);
    size_t off_fillc  = alloc((size_t)NN * 4);
    size_t off_easum  = alloc((size_t)NN * 2 * 4);
    size_t off_rowptr = alloc((size_t)(NN + 1) * 4);
    size_t off_bsum   = alloc((size_t)NBLK * 4);
    size_t off_srcs   = alloc((size_t)EF * 4);
    size_t off_fa0    = alloc((size_t)EF * 4);
    size_t off_fa1    = alloc((size_t)EF * 4);
    size_t off_axh    = alloc((size_t)NN * DD * 2);
    size_t off_axl    = alloc((size_t)NN * DD * 2);
    size_t off_ah     = alloc((size_t)NN * DD * 2);
    size_t off_al     = alloc((size_t)NN * DD * 2);
    size_t off_xl     = alloc((size_t)NN * 512 * 4);
    size_t off_xr     = alloc((size_t)NN * 512 * 2);   // bf16
    size_t off_w2th   = alloc((size_t)1024 * 128 * 2);
    size_t off_w2tl   = alloc((size_t)1024 * 128 * 2);
    size_t off_wfth   = alloc((size_t)128 * 128 * 2);
    size_t off_wftl   = alloc((size_t)128 * 128 * 2);
    size_t off_bias2  = alloc((size_t)1024 * 4);
    size_t need = o;

    bool ok = (n_in == 12) && d_ws != nullptr && ws_size >= need
           && out_size == NN * DD
           && in_sizes[0] == NN * DD && in_sizes[1] == 2 * NE
           && in_sizes[2] == NE * 2 && in_sizes[3] == 128 * 128
           && in_sizes[5] == 128 * 512 && in_sizes[9] == 2 * 512
           && in_sizes[10] == 4 * 128 && in_sizes[11] == 128;
    if (!ok) {
        k_zero_f<<<(NN * DD + 255) / 256, 256, 0, stream>>>((float*)d_out, NN * DD);
        return;
    }

    const float* x        = (const float*)d_in[0];
    const int*   ei       = (const int*)d_in[1];
    const float* ea       = (const float*)d_in[2];
    const float* Wf       = (const float*)d_in[3];
    const float* bf       = (const float*)d_in[4];
    const float* Wl       = (const float*)d_in[5];
    const float* bl       = (const float*)d_in[6];
    const float* Wr       = (const float*)d_in[7];
    const float* br       = (const float*)d_in[8];
    const float* We       = (const float*)d_in[9];
    const float* att      = (const float*)d_in[10];
    const float* bias_out = (const float*)d_in[11];

    char* base = (char*)d_ws;
    int*   cnt    = (int*)(base + off_cnt);
    int*   fillc  = (int*)(base + off_fillc);
    float* ea_sum = (float*)(base + off_easum);
    int*   rowptr = (int*)(base + off_rowptr);
    int*   bsum   = (int*)(base + off_bsum);
    int*   srcs   = (int*)(base + off_srcs);
    float* fa0    = (float*)(base + off_fa0);
    float* fa1    = (float*)(base + off_fa1);
    u16*   Axh    = (u16*)(base + off_axh);
    u16*   Axl    = (u16*)(base + off_axl);
    u16*   Ah     = (u16*)(base + off_ah);
    u16*   Al     = (u16*)(base + off_al);
    float* xl     = (float*)(base + off_xl);
    u16*   xr     = (u16*)(base + off_xr);
    u16*   W2Th   = (u16*)(base + off_w2th);
    u16*   W2Tl   = (u16*)(base + off_w2tl);
    u16*   WfTh   = (u16*)(base + off_wfth);
    u16*   WfTl   = (u16*)(base + off_wftl);
    float* bias2  = (float*)(base + off_bias2);

    int zero_ints = (int)((off_easum + (size_t)NN * 2 * 4 - off_cnt) / 4);
    k_zero_i<<<(zero_ints + 255) / 256, 256, 0, stream>>>(cnt, zero_ints);

    int packb = (NPA + NPW + 255) / 256;
    k_degpack<<<DEGB + packb, 256, 0, stream>>>(ei, ea, x, Wl, Wr, bl, br, Wf,
                                                cnt, ea_sum, Axh, Axl,
                                                W2Th, W2Tl, WfTh, WfTl, bias2);
    k_scan_a<<<NBLK, 512, 0, stream>>>(cnt, rowptr, bsum);
    k_scan_c<<<(NN + 255) / 256, 256, 0, stream>>>(rowptr, bsum);
    k_fill<<<(NE + NN + 255) / 256, 256, 0, stream>>>(ei, ea, rowptr, fillc,
                                                      cnt, ea_sum, srcs, fa0, fa1);

    const int MT = (NN + 63) / 64;   // 313
    // grid: x = band group (fast), y = m-tile
    k_mgemm<1, 2><<<dim3(1, MT), 256, 0, stream>>>(Axh, Axl, WfTh, WfTl,
                                                   bf, nullptr, nullptr, Ah, Al, NN);

    for (int layer = 0; layer < 3; ++layer) {
        k_mgemm<0, 8><<<dim3(2, MT), 256, 0, stream>>>(Ah, Al, W2Th, W2Tl,
                                                       bias2, xl, xr, nullptr, nullptr, NN);
        int last = (layer == 2);
        k_gat<<<NN / 2, 256, 0, stream>>>(rowptr, srcs, fa0, fa1, xl, xr,
                                          We, att, bias_out, Ah, Al,
                                          (float*)d_out, last);
    }
}